// Round 2
// baseline (224.161 us; speedup 1.0000x reference)
//
#include <hip/hip_runtime.h>

#define NB 8192
#define NPTS 1024
#define NTHREADS 256
#define PPT (NPTS / NTHREADS)   // 4 consecutive points per thread

// Output layout (flat concat, float32):
//   R: [0, NB*9)           out[b*9 + i*3 + j]
//   t: [NB*9, NB*9+NB*3)   out[NB*9 + b*3 + i]
//   S: [NB*12, NB*13)      out[NB*12 + b]

__global__ __launch_bounds__(NTHREADS) void align_kernel(
    const float* __restrict__ x, const float* __restrict__ mu_x,
    const float* __restrict__ y, const float* __restrict__ mu_y,
    float* __restrict__ out)
{
    const int b   = blockIdx.x;
    const int tid = threadIdx.x;

    // Each thread owns points [4*tid, 4*tid+4): 12 consecutive floats = 3 float4.
    const float4* x4 = (const float4*)(x + (size_t)b * (NPTS * 3)) + 3 * tid;
    const float4* y4 = (const float4*)(y + (size_t)b * (NPTS * 3)) + 3 * tid;

    // Issue all 6 independent dwordx4 loads up front.
    const float4 xa = x4[0], xb4 = x4[1], xc4 = x4[2];
    const float4 ya = y4[0], yb4 = y4[1], yc4 = y4[2];

    const float mx0 = mu_x[b * 3 + 0], mx1 = mu_x[b * 3 + 1], mx2 = mu_x[b * 3 + 2];
    const float my0 = mu_y[b * 3 + 0], my1 = mu_y[b * 3 + 1], my2 = mu_y[b * 3 + 2];

    // Unpack 4 points per cloud.
    const float xp[4][3] = {{xa.x, xa.y, xa.z}, {xa.w, xb4.x, xb4.y},
                            {xb4.z, xb4.w, xc4.x}, {xc4.y, xc4.z, xc4.w}};
    const float yp[4][3] = {{ya.x, ya.y, ya.z}, {ya.w, yb4.x, yb4.y},
                            {yb4.z, yb4.w, yc4.x}, {yc4.y, yc4.z, yc4.w}};

    // 9 covariance accumulators + |xc|^2 + |yc|^2
    float v[11];
    #pragma unroll
    for (int i = 0; i < 11; ++i) v[i] = 0.0f;

    #pragma unroll
    for (int k = 0; k < PPT; ++k) {
        const float xd0 = xp[k][0] - mx0, xd1 = xp[k][1] - mx1, xd2 = xp[k][2] - mx2;
        const float yd0 = yp[k][0] - my0, yd1 = yp[k][1] - my1, yd2 = yp[k][2] - my2;
        v[0] += xd0 * yd0; v[1] += xd0 * yd1; v[2] += xd0 * yd2;
        v[3] += xd1 * yd0; v[4] += xd1 * yd1; v[5] += xd1 * yd2;
        v[6] += xd2 * yd0; v[7] += xd2 * yd1; v[8] += xd2 * yd2;
        v[9]  += xd0 * xd0 + xd1 * xd1 + xd2 * xd2;
        v[10] += yd0 * yd0 + yd1 * yd1 + yd2 * yd2;
    }

    // Wave-level butterfly reduction (wave = 64 lanes on CDNA)
    #pragma unroll
    for (int off = 32; off >= 1; off >>= 1) {
        #pragma unroll
        for (int i = 0; i < 11; ++i) v[i] += __shfl_xor(v[i], off, 64);
    }

    __shared__ float sred[4][11];
    const int wave = tid >> 6;
    const int lane = tid & 63;
    if (lane == 0) {
        #pragma unroll
        for (int i = 0; i < 11; ++i) sred[wave][i] = v[i];
    }
    __syncthreads();

    if (tid == 0) {
        float a[11];
        #pragma unroll
        for (int i = 0; i < 11; ++i)
            a[i] = sred[0][i] + sred[1][i] + sred[2][i] + sred[3][i];

        // Q = cov (row-major: Q[d*3+e] = sum_n xc[n,d]*yc[n,e])
        float Q[9];
        #pragma unroll
        for (int i = 0; i < 9; ++i) Q[i] = a[i];

        // Scaled Newton iteration for the orthogonal polar factor:
        //   Q <- 0.5 * (g*Q + (1/g) * Q^-T),  g = sqrt(||Q^-1||_F / ||Q||_F)
        // Q^-T = cof(Q) / det(Q). Converges to U*V^T of the SVD.
        #pragma unroll
        for (int it = 0; it < 9; ++it) {
            float C[9];
            C[0] = Q[4] * Q[8] - Q[5] * Q[7];
            C[1] = Q[5] * Q[6] - Q[3] * Q[8];
            C[2] = Q[3] * Q[7] - Q[4] * Q[6];
            C[3] = Q[2] * Q[7] - Q[1] * Q[8];
            C[4] = Q[0] * Q[8] - Q[2] * Q[6];
            C[5] = Q[1] * Q[6] - Q[0] * Q[7];
            C[6] = Q[1] * Q[5] - Q[2] * Q[4];
            C[7] = Q[2] * Q[3] - Q[0] * Q[5];
            C[8] = Q[0] * Q[4] - Q[1] * Q[3];
            const float det = Q[0] * C[0] + Q[1] * C[1] + Q[2] * C[2];
            const float invdet = 1.0f / det;

            float nq = 0.0f, nc = 0.0f;
            #pragma unroll
            for (int i = 0; i < 9; ++i) { nq += Q[i] * Q[i]; nc += C[i] * C[i]; }
            // ||Q^-1||_F = ||C||_F * |invdet|;  g^2 = ||Q^-1||_F/||Q||_F
            const float g  = sqrtf(sqrtf(nc * invdet * invdet / nq));
            const float hg = 0.5f * g;
            const float hi = 0.5f * invdet / g;
            #pragma unroll
            for (int i = 0; i < 9; ++i) Q[i] = hg * Q[i] + hi * C[i];
        }

        // R
        #pragma unroll
        for (int i = 0; i < 9; ++i) out[(size_t)b * 9 + i] = Q[i];

        // t = mu_y - R @ mu_x
        float* tout = out + (size_t)NB * 9 + (size_t)b * 3;
        tout[0] = my0 - (Q[0] * mx0 + Q[1] * mx1 + Q[2] * mx2);
        tout[1] = my1 - (Q[3] * mx0 + Q[4] * mx1 + Q[5] * mx2);
        tout[2] = my2 - (Q[6] * mx0 + Q[7] * mx1 + Q[8] * mx2);

        // scale = ||yc||_F / (||xc||_F + 1e-6)
        out[(size_t)NB * 12 + b] = sqrtf(a[10]) / (sqrtf(a[9]) + 1e-6f);
    }
}

extern "C" void kernel_launch(void* const* d_in, const int* in_sizes, int n_in,
                              void* d_out, int out_size, void* d_ws, size_t ws_size,
                              hipStream_t stream) {
    const float* x    = (const float*)d_in[0];
    const float* mu_x = (const float*)d_in[1];
    const float* y    = (const float*)d_in[2];
    const float* mu_y = (const float*)d_in[3];
    float* out = (float*)d_out;
    align_kernel<<<dim3(NB), dim3(NTHREADS), 0, stream>>>(x, mu_x, y, mu_y, out);
}

// Round 3
// 219.759 us; speedup vs baseline: 1.0200x; 1.0200x over previous
//
#include <hip/hip_runtime.h>

#define NB 8192
#define NPTS 1024

// Output layout (flat concat, float32):
//   R: [0, NB*9)           out[b*9 + i*3 + j]
//   t: [NB*9, NB*12)       out[NB*9 + b*3 + i]
//   S: [NB*12, NB*13)      out[NB*12 + b]
//
// Workspace: ws[b*12 + 0..8] = cov (row-major), ws[b*12+9] = |xc|^2,
//            ws[b*12+10] = |yc|^2, [11] = pad (stride 12 floats = 3 float4).

// ---------------- Kernel A: streaming covariance reduction ----------------
// One wave per batch; 4 waves (one block of 256) cover 4 batches. No LDS,
// no __syncthreads — per-batch reduction is a single 64-lane butterfly.
__global__ __launch_bounds__(256) void cov_kernel(
    const float* __restrict__ x, const float* __restrict__ y,
    const float* __restrict__ mu_x, const float* __restrict__ mu_y,
    float* __restrict__ ws)
{
    const int wave = threadIdx.x >> 6;
    const int lane = threadIdx.x & 63;
    const int b    = blockIdx.x * 4 + wave;

    const float4* x4 = (const float4*)(x + (size_t)b * (NPTS * 3));
    const float4* y4 = (const float4*)(y + (size_t)b * (NPTS * 3));

    const float mx0 = mu_x[b * 3 + 0], mx1 = mu_x[b * 3 + 1], mx2 = mu_x[b * 3 + 2];
    const float my0 = mu_y[b * 3 + 0], my1 = mu_y[b * 3 + 1], my2 = mu_y[b * 3 + 2];

    float v[11];
    #pragma unroll
    for (int i = 0; i < 11; ++i) v[i] = 0.0f;

    // 16 points per lane: 4 chunks x (3 float4 per cloud). Chunk c, lane l
    // owns points 4*(64c+l)..+3 -> float4 indices 3*(64c+l)..+2 (coalesced).
    #pragma unroll
    for (int c = 0; c < 4; ++c) {
        const int base = 3 * (c * 64 + lane);
        const float4 xa = x4[base + 0], xb4 = x4[base + 1], xc4 = x4[base + 2];
        const float4 ya = y4[base + 0], yb4 = y4[base + 1], yc4 = y4[base + 2];

        const float xp[4][3] = {{xa.x, xa.y, xa.z}, {xa.w, xb4.x, xb4.y},
                                {xb4.z, xb4.w, xc4.x}, {xc4.y, xc4.z, xc4.w}};
        const float yp[4][3] = {{ya.x, ya.y, ya.z}, {ya.w, yb4.x, yb4.y},
                                {yb4.z, yb4.w, yc4.x}, {yc4.y, yc4.z, yc4.w}};

        #pragma unroll
        for (int k = 0; k < 4; ++k) {
            const float xd0 = xp[k][0] - mx0, xd1 = xp[k][1] - mx1, xd2 = xp[k][2] - mx2;
            const float yd0 = yp[k][0] - my0, yd1 = yp[k][1] - my1, yd2 = yp[k][2] - my2;
            v[0] += xd0 * yd0; v[1] += xd0 * yd1; v[2] += xd0 * yd2;
            v[3] += xd1 * yd0; v[4] += xd1 * yd1; v[5] += xd1 * yd2;
            v[6] += xd2 * yd0; v[7] += xd2 * yd1; v[8] += xd2 * yd2;
            v[9]  += xd0 * xd0 + xd1 * xd1 + xd2 * xd2;
            v[10] += yd0 * yd0 + yd1 * yd1 + yd2 * yd2;
        }
    }

    // 64-lane butterfly (single reduction per batch).
    #pragma unroll
    for (int off = 32; off >= 1; off >>= 1) {
        #pragma unroll
        for (int i = 0; i < 11; ++i) v[i] += __shfl_xor(v[i], off, 64);
    }

    if (lane == 0) {
        float* w = ws + (size_t)b * 12;
        #pragma unroll
        for (int i = 0; i < 11; ++i) w[i] = v[i];
    }
}

// ---------------- Kernel B: per-thread polar factor + epilogue ----------------
// One batch per thread; all 64 lanes of every wave do independent Newton
// iterations -> full VALU utilization (vs 1/64 in the fused version).
__global__ __launch_bounds__(256) void polar_kernel(
    const float* __restrict__ ws,
    const float* __restrict__ mu_x, const float* __restrict__ mu_y,
    float* __restrict__ out)
{
    const int b = blockIdx.x * 256 + threadIdx.x;

    const float4* w4 = (const float4*)ws + 3 * (size_t)b;
    const float4 w0 = w4[0], w1 = w4[1], w2 = w4[2];

    float Q[9] = {w0.x, w0.y, w0.z, w0.w, w1.x, w1.y, w1.z, w1.w, w2.x};
    const float nxx = w2.y;   // |xc|^2
    const float nyy = w2.z;   // |yc|^2

    // Scaled Newton iteration for the orthogonal polar factor:
    //   Q <- 0.5 * (g*Q + (1/g) * Q^-T),  g = sqrt(||Q^-1||_F / ||Q||_F)
    // Q^-T = cof(Q)/det(Q); converges to U*V^T of the SVD (incl. det<0).
    #pragma unroll
    for (int it = 0; it < 11; ++it) {
        float C[9];
        C[0] = Q[4] * Q[8] - Q[5] * Q[7];
        C[1] = Q[5] * Q[6] - Q[3] * Q[8];
        C[2] = Q[3] * Q[7] - Q[4] * Q[6];
        C[3] = Q[2] * Q[7] - Q[1] * Q[8];
        C[4] = Q[0] * Q[8] - Q[2] * Q[6];
        C[5] = Q[1] * Q[6] - Q[0] * Q[7];
        C[6] = Q[1] * Q[5] - Q[2] * Q[4];
        C[7] = Q[2] * Q[3] - Q[0] * Q[5];
        C[8] = Q[0] * Q[4] - Q[1] * Q[3];
        const float det = Q[0] * C[0] + Q[1] * C[1] + Q[2] * C[2];
        const float invdet = 1.0f / det;

        float nq = 0.0f, nc = 0.0f;
        #pragma unroll
        for (int i = 0; i < 9; ++i) { nq += Q[i] * Q[i]; nc += C[i] * C[i]; }
        const float g  = sqrtf(sqrtf(nc * invdet * invdet / nq));
        const float hg = 0.5f * g;
        const float hi = 0.5f * invdet / g;
        #pragma unroll
        for (int i = 0; i < 9; ++i) Q[i] = hg * Q[i] + hi * C[i];
    }

    const float mx0 = mu_x[b * 3 + 0], mx1 = mu_x[b * 3 + 1], mx2 = mu_x[b * 3 + 2];
    const float my0 = mu_y[b * 3 + 0], my1 = mu_y[b * 3 + 1], my2 = mu_y[b * 3 + 2];

    #pragma unroll
    for (int i = 0; i < 9; ++i) out[(size_t)b * 9 + i] = Q[i];

    float* tout = out + (size_t)NB * 9 + (size_t)b * 3;
    tout[0] = my0 - (Q[0] * mx0 + Q[1] * mx1 + Q[2] * mx2);
    tout[1] = my1 - (Q[3] * mx0 + Q[4] * mx1 + Q[5] * mx2);
    tout[2] = my2 - (Q[6] * mx0 + Q[7] * mx1 + Q[8] * mx2);

    out[(size_t)NB * 12 + b] = sqrtf(nyy) / (sqrtf(nxx) + 1e-6f);
}

extern "C" void kernel_launch(void* const* d_in, const int* in_sizes, int n_in,
                              void* d_out, int out_size, void* d_ws, size_t ws_size,
                              hipStream_t stream) {
    const float* x    = (const float*)d_in[0];
    const float* mu_x = (const float*)d_in[1];
    const float* y    = (const float*)d_in[2];
    const float* mu_y = (const float*)d_in[3];
    float* out = (float*)d_out;
    float* ws  = (float*)d_ws;   // needs NB*12*4 = 384 KiB

    cov_kernel<<<dim3(NB / 4), dim3(256), 0, stream>>>(x, y, mu_x, mu_y, ws);
    polar_kernel<<<dim3(NB / 256), dim3(256), 0, stream>>>(ws, mu_x, mu_y, out);
}